// Round 4
// baseline (17926.190 us; speedup 1.0000x reference)
//
#include <hip/hip_runtime.h>

typedef unsigned short u16;
typedef unsigned int u32;
typedef unsigned long long u64;

typedef short bf16x8 __attribute__((ext_vector_type(8)));
typedef float f32x4 __attribute__((ext_vector_type(4)));

#define NB 64
#define NS 512
#define ND 768
#define NH 384
#define NT_OUT 22
#define S2 272           // materialized xg time extent (n[b] <= 256 < 272)
#define S2R 273          // xg rows: 272 GEMM rows + 1 bias row (index 272)
#define NG 1536          // 4*H
#define MGEMM (NB*S2)    // 17408

__device__ __forceinline__ u16 f2b(float f) {
    u32 u = __float_as_uint(f);
    u32 r = (u + 0x7fffu + ((u >> 16) & 1u)) >> 16;
    return (u16)r;
}
__device__ __forceinline__ float b2f(u16 s) { return __uint_as_float(((u32)s) << 16); }

__device__ __forceinline__ float sigm(float x) {
    return __builtin_amdgcn_rcpf(1.f + __expf(-x));
}
__device__ __forceinline__ float tanh_(float x) {
    return 1.f - 2.f * __builtin_amdgcn_rcpf(1.f + __expf(2.f * x));
}

__device__ __forceinline__ void gl_lds16(const void* g, void* l) {
    __builtin_amdgcn_global_load_lds(
        (const __attribute__((address_space(1))) unsigned int*)g,
        (__attribute__((address_space(3))) unsigned int*)l, 16, 0, 0);
}

// ---------------- prep: align/gather -> embeds bf16 [64][272][768] ----------------
__global__ void k_prep(const float* __restrict__ hidden, const int* __restrict__ start_ids,
                       const int* __restrict__ masks, u16* __restrict__ embeds) {
    int b = blockIdx.x >> 2;
    int quarter = blockIdx.x & 3;
    int tid = threadIdx.x;
    __shared__ int red[256];
    int cn = 0, cm = 0;
    for (int s = tid; s < NS; s += 256) {
        cn += (start_ids[b * NS + s] >= 0) ? 1 : 0;
        cm += (masks[b * NS + s] != 0) ? 1 : 0;
    }
    red[tid] = cn + (cm << 16);
    __syncthreads();
    #pragma unroll
    for (int off = 128; off > 0; off >>= 1) {
        if (tid < off) red[tid] += red[tid + off];
        __syncthreads();
    }
    int n = red[0] & 0xffff;
    int slen = red[0] >> 16;
    n = min(max(n, 1), NS);
    int last = start_ids[b * NS + n - 1];
    for (int t = quarter * 68; t < quarter * 68 + 68; ++t) {
        int idx;
        if (t == 0) idx = 0;
        else if (t < n) idx = start_ids[b * NS + t] - 1;
        else if (t == n) idx = last;
        else idx = 0;
        idx = min(max(idx, 0), NS - 1);
        bool keep = t < slen;
        const float* src = hidden + ((size_t)b * NS + idx) * ND;
        u16* dst = embeds + ((size_t)b * S2 + t) * ND;
        if (tid < 192) {
            float4 v = keep ? *(const float4*)(src + tid * 4) : make_float4(0.f, 0.f, 0.f, 0.f);
            union { u16 u[4]; uint2 q; } pk;
            pk.u[0] = f2b(v.x); pk.u[1] = f2b(v.y); pk.u[2] = f2b(v.z); pk.u[3] = f2b(v.w);
            *(uint2*)(dst + tid * 4) = pk.q;
        }
    }
}

// ---------------- weights: cast W_ih (cat) to bf16, bias sums, h0 cast, xg bias row ----
__global__ void k_weights(const float* __restrict__ wf, const float* __restrict__ wb,
                          const float* __restrict__ bihf, const float* __restrict__ bhhf,
                          const float* __restrict__ bihb, const float* __restrict__ bhhb,
                          const float* __restrict__ h0,
                          u16* __restrict__ wihcat, float* __restrict__ biascat,
                          u16* __restrict__ h0buf, u16* __restrict__ xg) {
    int i0 = blockIdx.x * blockDim.x + threadIdx.x;
    int NTH = gridDim.x * blockDim.x;
    for (size_t i = i0; i < (size_t)2 * NG * ND; i += NTH) {
        size_t nrow = i / ND, k = i - nrow * ND;
        float v = (nrow < NG) ? wf[nrow * ND + k] : wb[(nrow - NG) * ND + k];
        wihcat[i] = f2b(v);
    }
    for (int i = i0; i < 2 * NG; i += NTH)
        biascat[i] = (i < NG) ? bihf[i] + bhhf[i] : bihb[i - NG] + bhhb[i - NG];
    for (int i = i0; i < 2 * NB * NH; i += NTH) h0buf[i] = f2b(h0[i]);
    // bias row (t = 272) of xg: value = bih + bhh (what the GEMM would give for x = 0)
    for (size_t i = i0; i < (size_t)2 * NB * NG; i += NTH) {
        int dd = (int)(i / (NB * NG));
        int rem = (int)(i - (size_t)dd * NB * NG);
        int b = rem / NG, col = rem - b * NG;
        float v = (dd == 0) ? bihf[col] + bhhf[col] : bihb[col] + bhhb[col];
        xg[((size_t)(dd * NB + b) * S2R + S2) * NG + col] = f2b(v);
    }
}

// ---------------- pack Whh into gate-interleaved MFMA B-fragment order ----------------
// packed col p = j*4 + gate  (j in [0,384), gate in [0,4))
// layout: [d][wid(16)][nt(6)][ks(12)][lane(64)][8]; wave wid owns p in [wid*96, wid*96+96)
__global__ void k_packwhh(const float* __restrict__ whhf, const float* __restrict__ whhb,
                          u16* __restrict__ pack) {
    int ft = blockIdx.x * 256 + threadIdx.x;
    if (ft >= 2 * 16 * 6 * 12 * 64) return;
    int lane = ft & 63;
    int grp = ft >> 6;
    int ks = grp % 12; grp /= 12;
    int nt = grp % 6;  grp /= 6;
    int wid = grp & 15;
    int d = grp >> 4;
    const float* W = d ? whhb : whhf;
    int p = wid * 96 + nt * 16 + (lane & 15);
    int j = p >> 2, gate = p & 3;
    int row = gate * NH + j;              // W_hh row (output dim)
    int k0 = ks * 32 + (lane >> 4) * 8;
    u16* dst = pack + (size_t)ft * 8;
    #pragma unroll
    for (int e = 0; e < 8; e++) dst[e] = f2b(W[(size_t)row * NH + k0 + e]);
}

// ---------------- GEMM: xg[d][b][t<272][1536] (bf16, gate-major cols) ----------------
__launch_bounds__(256, 2)
__global__ void k_gemm(const u16* __restrict__ A, const u16* __restrict__ Bw,
                       const float* __restrict__ biascat, u16* __restrict__ xg) {
    __shared__ u16 As[128 * 32];
    __shared__ u16 Bs[128 * 32];
    int tid = threadIdx.x;
    int lane = tid & 63, wid = tid >> 6;
    int l15 = lane & 15, q4 = lane >> 4;
    int bn = blockIdx.x;   // 24 tiles of N=3072
    int bm = blockIdx.y;   // 136 tiles of M=17408
    int wm = (wid >> 1) * 64, wn = (wid & 1) * 64;
    f32x4 acc[4][4] = {};
    for (int k0 = 0; k0 < ND; k0 += 32) {
        #pragma unroll
        for (int j = 0; j < 2; j++) {
            int fl = tid + j * 256;
            int row = fl >> 2, cb = fl & 3;
            const u16* ga = A + (size_t)(bm * 128 + row) * ND + k0 + cb * 8;
            gl_lds16(ga, &As[(size_t)(wid * 64 + j * 256) * 8]);
            const u16* gb = Bw + (size_t)(bn * 128 + row) * ND + k0 + cb * 8;
            gl_lds16(gb, &Bs[(size_t)(wid * 64 + j * 256) * 8]);
        }
        __syncthreads();
        bf16x8 af[4], bf[4];
        #pragma unroll
        for (int mt = 0; mt < 4; mt++)
            af[mt] = *(const bf16x8*)&As[(wm + mt * 16 + l15) * 32 + q4 * 8];
        #pragma unroll
        for (int nt = 0; nt < 4; nt++)
            bf[nt] = *(const bf16x8*)&Bs[(wn + nt * 16 + l15) * 32 + q4 * 8];
        #pragma unroll
        for (int mt = 0; mt < 4; mt++)
            #pragma unroll
            for (int nt = 0; nt < 4; nt++)
                acc[mt][nt] = __builtin_amdgcn_mfma_f32_16x16x32_bf16(af[mt], bf[nt], acc[mt][nt], 0, 0, 0);
        __syncthreads();
    }
    #pragma unroll
    for (int nt = 0; nt < 4; nt++) {
        int gn = bn * 128 + wn + nt * 16 + l15;
        int d = gn >= NG ? 1 : 0;
        int col = gn - d * NG;
        float bias = biascat[gn];
        #pragma unroll
        for (int mt = 0; mt < 4; mt++) {
            #pragma unroll
            for (int r = 0; r < 4; r++) {
                int m = bm * 128 + wm + mt * 16 + q4 * 4 + r;
                int b = m / S2, t = m - b * S2;
                float v = acc[mt][nt][r] + bias;
                xg[((size_t)(d * NB + b) * S2R + t) * NG + col] = f2b(v);
            }
        }
    }
}

// ---------------- recurrence: 8 WGs x 1024 threads; NO cross-WG sync ----------------
// WG = (dir d, batch-group g of 16). 16 waves; wave wid owns packed cols [wid*96, +96)
// = all 4 gates of j in [wid*24, wid*24+24). Whh stationary in regs (288/wave).
// h double-buffered in LDS; one __syncthreads per step.
__launch_bounds__(1024, 1)
__global__ void k_recur(const u16* __restrict__ whhpack, const u16* __restrict__ xg,
                        const u16* __restrict__ h0buf, const float* __restrict__ c0,
                        u16* __restrict__ hout) {
    int bid = blockIdx.x;          // 0..7
    int d = bid >> 2, g = bid & 3;
    int tid = threadIdx.x;
    int wid = tid >> 6;            // wave 0..15
    int lane = tid & 63;
    int q4 = lane >> 4, l15 = lane & 15;
    int cq = lane & 3;             // quad pos; after transpose = gate index
    int jq = (lane >> 2) & 3;      // j' within 16-col tile
    int bb = q4 * 4 + cq;          // batch (0..15) this lane owns post-transpose

    __shared__ u16 hswz[2][12][4][16][8];   // [buf][ks][q4][batch][e] 24.6 KB

    // stationary Whh B-fragments: 72 x 4 regs = 288
    bf16x8 bfr[6][12];
    #pragma unroll
    for (int nt = 0; nt < 6; nt++)
        #pragma unroll
        for (int ks = 0; ks < 12; ks++)
            bfr[nt][ks] = *(const bf16x8*)(whhpack +
                ((size_t)(((d * 16 + wid) * 6 + nt) * 12 + ks) * 64 + lane) * 8);

    // h0 -> LDS buffer 0
    for (int i = tid; i < 16 * NH; i += 1024) {
        int b2 = i / NH, j = i - b2 * NH;
        hswz[0][j >> 5][(j >> 3) & 3][b2][j & 7] =
            h0buf[((size_t)(d * NB + g * 16 + b2)) * NH + j];
    }
    // c-state in regs: lane owns (bb, j = wid*24 + nt*4 + jq) for nt=0..5
    float cre[6];
    #pragma unroll
    for (int nt = 0; nt < 6; nt++)
        cre[nt] = c0[((size_t)(d * NB + g * 16 + bb)) * NH + wid * 24 + nt * 4 + jq];

    // xg column (gate-major) for this lane's C-space col p = wid*96+nt*16+l15
    int xcol[6];
    #pragma unroll
    for (int nt = 0; nt < 6; nt++) {
        int p = wid * 96 + nt * 16 + l15;
        xcol[nt] = (p & 3) * NH + (p >> 2);
    }

    const u16* xgd = xg + (size_t)d * NB * S2R * NG;
    float ci[6][4];
    auto preload = [&](int it2) {
        int s2 = d ? (NS - 1 - it2) : it2;
        if (s2 > S2) s2 = S2;                 // bias row
        #pragma unroll
        for (int r = 0; r < 4; r++) {
            const u16* xrow = xgd + ((size_t)(g * 16 + q4 * 4 + r) * S2R + s2) * NG;
            #pragma unroll
            for (int nt = 0; nt < 6; nt++)
                ci[nt][r] = b2f(xrow[xcol[nt]]);
        }
    };
    preload(0);
    __syncthreads();

    #pragma unroll 1
    for (int it = 0; it < NS; ++it) {
        int s = d ? (NS - 1 - it) : it;
        int rb = it & 1, wb2 = rb ^ 1;

        bf16x8 af[12];
        #pragma unroll
        for (int ks = 0; ks < 12; ks++)
            af[ks] = *(const bf16x8*)&hswz[rb][ks][q4][l15][0];

        f32x4 acc[6];
        #pragma unroll
        for (int nt = 0; nt < 6; nt++) {
            acc[nt][0] = ci[nt][0]; acc[nt][1] = ci[nt][1];
            acc[nt][2] = ci[nt][2]; acc[nt][3] = ci[nt][3];
        }
        #pragma unroll
        for (int ks = 0; ks < 12; ks++)
            #pragma unroll
            for (int nt = 0; nt < 6; nt++)
                acc[nt] = __builtin_amdgcn_mfma_f32_16x16x32_bf16(af[ks], bfr[nt][ks], acc[nt], 0, 0, 0);

        if (it < NS - 1) preload(it + 1);   // hides under MFMA/cell

        // per-tile quad transpose + cell update (wave-local, no LDS round-trip)
        bool o1 = (cq & 1) != 0, o2 = (cq & 2) != 0;
        u16* hob = hout + (((size_t)(d * NB + g * 16 + bb)) * NS + s) * NH;
        #pragma unroll
        for (int nt = 0; nt < 6; nt++) {
            float m0 = acc[nt][0], m1 = acc[nt][1], m2 = acc[nt][2], m3 = acc[nt][3];
            float r01 = __shfl_xor(o1 ? m0 : m1, 1);
            float a0 = o1 ? r01 : m0;
            float a1 = o1 ? m1 : r01;
            float r23 = __shfl_xor(o1 ? m2 : m3, 1);
            float a2 = o1 ? r23 : m2;
            float a3 = o1 ? m3 : r23;
            float r02 = __shfl_xor(o2 ? a0 : a2, 2);
            float gi = o2 ? r02 : a0;
            float gg2 = o2 ? a2 : r02;
            float r13 = __shfl_xor(o2 ? a1 : a3, 2);
            float gf = o2 ? r13 : a1;
            float go = o2 ? a3 : r13;
            // gi,gf,gg2,go = gates i,f,g,o for (batch bb, j)
            float c = cre[nt];
            float cn = sigm(gf) * c + sigm(gi) * tanh_(gg2);
            float hn = sigm(go) * tanh_(cn);
            cre[nt] = cn;
            u16 hb = f2b(hn);
            int j = wid * 24 + nt * 4 + jq;
            hswz[wb2][j >> 5][(j >> 3) & 3][bb][j & 7] = hb;
            hob[j] = hb;
        }
        __syncthreads();
    }
}

// ---------------- final linear: out[b,t,22] = [hf|hb] @ WlinT + blin ----------------
__global__ void k_final(const u16* __restrict__ hout, const float* __restrict__ wlin,
                        const float* __restrict__ blin, float* __restrict__ out) {
    int r = blockIdx.x * 256 + threadIdx.x;   // 0..32767
    int b = r >> 9, t = r & 511;
    const u16* hf = hout + ((size_t)b * NS + t) * NH;
    const u16* hb = hout + ((size_t)(NB + b) * NS + t) * NH;
    float acc[NT_OUT];
    #pragma unroll
    for (int tt = 0; tt < NT_OUT; tt++) acc[tt] = blin[tt];
    #pragma unroll 1
    for (int half = 0; half < 2; half++) {
        const u16* hp = half ? hb : hf;
        #pragma unroll 1
        for (int k8 = 0; k8 < NH / 8; k8++) {
            uint4 pk = *(const uint4*)(hp + k8 * 8);
            float x[8];
            x[0] = __uint_as_float(pk.x << 16); x[1] = __uint_as_float(pk.x & 0xffff0000u);
            x[2] = __uint_as_float(pk.y << 16); x[3] = __uint_as_float(pk.y & 0xffff0000u);
            x[4] = __uint_as_float(pk.z << 16); x[5] = __uint_as_float(pk.z & 0xffff0000u);
            x[6] = __uint_as_float(pk.w << 16); x[7] = __uint_as_float(pk.w & 0xffff0000u);
            int kk = half * NH + k8 * 8;
            #pragma unroll
            for (int e = 0; e < 8; e++)
                #pragma unroll
                for (int tt = 0; tt < NT_OUT; tt++)
                    acc[tt] += x[e] * wlin[tt * (2 * NH) + kk + e];   // uniform -> s_load
        }
    }
    float* op = out + (size_t)r * NT_OUT;
    #pragma unroll
    for (int tt = 0; tt < NT_OUT; tt++) op[tt] = acc[tt];
}

extern "C" void kernel_launch(void* const* d_in, const int* in_sizes, int n_in,
                              void* d_out, int out_size, void* d_ws, size_t ws_size,
                              hipStream_t stream) {
    const float* hidden = (const float*)d_in[0];
    const float* h0     = (const float*)d_in[1];
    const float* c0     = (const float*)d_in[2];
    const float* Wihf   = (const float*)d_in[3];
    const float* Whhf   = (const float*)d_in[4];
    const float* bihf   = (const float*)d_in[5];
    const float* bhhf   = (const float*)d_in[6];
    const float* Wihb   = (const float*)d_in[7];
    const float* Whhb   = (const float*)d_in[8];
    const float* bihb   = (const float*)d_in[9];
    const float* bhhb   = (const float*)d_in[10];
    const float* Wlin   = (const float*)d_in[11];
    const float* blin   = (const float*)d_in[12];
    const int* start_ids = (const int*)d_in[13];
    const int* masks     = (const int*)d_in[14];
    float* out = (float*)d_out;

    char* ws = (char*)d_ws;
    size_t off = 0;
    auto alloc = [&](size_t bytes) { void* p = ws + off; off += (bytes + 255) & ~(size_t)255; return p; };
    u16* embeds   = (u16*)alloc((size_t)MGEMM * ND * 2);           // 26.7 MB
    u16* wihcat   = (u16*)alloc((size_t)2 * NG * ND * 2);          // 4.7 MB
    float* biascat = (float*)alloc((size_t)2 * NG * 4);            // 12 KB
    u16* whhpack  = (u16*)alloc((size_t)2 * NG * NH * 2);          // 2.36 MB
    u16* h0buf    = (u16*)alloc((size_t)2 * NB * NH * 2);          // 98 KB
    u16* xg       = (u16*)alloc((size_t)2 * NB * S2R * NG * 2);    // 107.4 MB
    u16* hout     = (u16*)alloc((size_t)2 * NB * NS * NH * 2);     // 50.3 MB

    k_prep<<<256, 256, 0, stream>>>(hidden, start_ids, masks, embeds);
    k_weights<<<512, 256, 0, stream>>>(Wihf, Wihb, bihf, bhhf, bihb, bhhb, h0,
                                       wihcat, biascat, h0buf, xg);
    k_packwhh<<<576, 256, 0, stream>>>(Whhf, Whhb, whhpack);
    dim3 ggrid(2 * NG / 128, MGEMM / 128);
    k_gemm<<<ggrid, 256, 0, stream>>>(embeds, wihcat, biascat, xg);
    k_recur<<<8, 1024, 0, stream>>>(whhpack, xg, h0buf, c0, hout);
    k_final<<<128, 256, 0, stream>>>(hout, Wlin, blin, out);
}

// Round 5
// 3034.489 us; speedup vs baseline: 5.9075x; 5.9075x over previous
//
#include <hip/hip_runtime.h>

typedef unsigned short u16;
typedef unsigned int u32;
typedef unsigned long long u64;

typedef short bf16x8 __attribute__((ext_vector_type(8)));
typedef float f32x4 __attribute__((ext_vector_type(4)));

#define NB 64
#define NS 512
#define ND 768
#define NH 384
#define NT_OUT 22
#define S2 272           // materialized xg time extent (n[b] <= 256 < 272)
#define NG 1536          // 4*H
#define MGEMM (NB*S2)    // 17408

__device__ __forceinline__ u16 f2b(float f) {
    u32 u = __float_as_uint(f);
    u32 r = (u + 0x7fffu + ((u >> 16) & 1u)) >> 16;
    return (u16)r;
}
__device__ __forceinline__ float b2f(u16 s) { return __uint_as_float(((u32)s) << 16); }

__device__ __forceinline__ float sigm(float x) {
    return __builtin_amdgcn_rcpf(1.f + __expf(-x));
}
__device__ __forceinline__ float tanh_(float x) {
    return 1.f - 2.f * __builtin_amdgcn_rcpf(1.f + __expf(2.f * x));
}

__device__ __forceinline__ void gl_lds16(const void* g, void* l) {
    __builtin_amdgcn_global_load_lds(
        (const __attribute__((address_space(1))) unsigned int*)g,
        (__attribute__((address_space(3))) unsigned int*)l, 16, 0, 0);
}

// ---------------- prep: align/gather -> embeds bf16 [64][272][768] ----------------
__global__ void k_prep(const float* __restrict__ hidden, const int* __restrict__ start_ids,
                       const int* __restrict__ masks, u16* __restrict__ embeds) {
    int b = blockIdx.x >> 2;
    int quarter = blockIdx.x & 3;
    int tid = threadIdx.x;
    __shared__ int red[256];
    int cn = 0, cm = 0;
    for (int s = tid; s < NS; s += 256) {
        cn += (start_ids[b * NS + s] >= 0) ? 1 : 0;
        cm += (masks[b * NS + s] != 0) ? 1 : 0;
    }
    red[tid] = cn + (cm << 16);
    __syncthreads();
    #pragma unroll
    for (int off = 128; off > 0; off >>= 1) {
        if (tid < off) red[tid] += red[tid + off];
        __syncthreads();
    }
    int n = red[0] & 0xffff;
    int slen = red[0] >> 16;
    n = min(max(n, 1), NS);
    int last = start_ids[b * NS + n - 1];
    for (int t = quarter * 68; t < quarter * 68 + 68; ++t) {
        int idx;
        if (t == 0) idx = 0;
        else if (t < n) idx = start_ids[b * NS + t] - 1;
        else if (t == n) idx = last;
        else idx = 0;
        idx = min(max(idx, 0), NS - 1);
        bool keep = t < slen;
        const float* src = hidden + ((size_t)b * NS + idx) * ND;
        u16* dst = embeds + ((size_t)b * S2 + t) * ND;
        if (tid < 192) {
            float4 v = keep ? *(const float4*)(src + tid * 4) : make_float4(0.f, 0.f, 0.f, 0.f);
            union { u16 u[4]; uint2 q; } pk;
            pk.u[0] = f2b(v.x); pk.u[1] = f2b(v.y); pk.u[2] = f2b(v.z); pk.u[3] = f2b(v.w);
            *(uint2*)(dst + tid * 4) = pk.q;
        }
    }
}

// ---------------- weights: cast W_ih (cat) to bf16, bias sums, h0 cast ----------------
__global__ void k_weights(const float* __restrict__ wf, const float* __restrict__ wb,
                          const float* __restrict__ bihf, const float* __restrict__ bhhf,
                          const float* __restrict__ bihb, const float* __restrict__ bhhb,
                          const float* __restrict__ h0,
                          u16* __restrict__ wihcat, float* __restrict__ biascat,
                          u16* __restrict__ h0buf) {
    int i0 = blockIdx.x * blockDim.x + threadIdx.x;
    int NTH = gridDim.x * blockDim.x;
    for (size_t i = i0; i < (size_t)2 * NG * ND; i += NTH) {
        size_t nrow = i / ND, k = i - nrow * ND;
        float v = (nrow < NG) ? wf[nrow * ND + k] : wb[(nrow - NG) * ND + k];
        wihcat[i] = f2b(v);
    }
    for (int i = i0; i < 2 * NG; i += NTH)
        biascat[i] = (i < NG) ? bihf[i] + bhhf[i] : bihb[i - NG] + bhhb[i - NG];
    for (int i = i0; i < 2 * NB * NH; i += NTH) h0buf[i] = f2b(h0[i]);
}

// ---------------- pack Whh into MFMA B-fragment order ----------------
// layout: [d][qc][w][nt][ks][lane][8]  (d:2, qc:4 j-chunk, w:4 gate, nt:6, ks:12)
__global__ void k_packwhh(const float* __restrict__ whhf, const float* __restrict__ whhb,
                          u16* __restrict__ pack) {
    int ft = blockIdx.x * 256 + threadIdx.x;
    if (ft >= 2 * 4 * 4 * 6 * 12 * 64) return;
    int lane = ft & 63;
    int grp = ft >> 6;
    int ks = grp % 12; grp /= 12;
    int nt = grp % 6;  grp /= 6;
    int w  = grp & 3;  grp >>= 2;
    int qc = grp & 3;
    int d  = grp >> 2;
    const float* W = d ? whhb : whhf;
    int col = w * NH + qc * 96 + nt * 16 + (lane & 15);
    int k0 = ks * 32 + (lane >> 4) * 8;
    u16* dst = pack + (size_t)ft * 8;
    #pragma unroll
    for (int e = 0; e < 8; e++) dst[e] = f2b(W[(size_t)col * NH + k0 + e]);
}

// ---------------- GEMM: xg[d][b][t<272][1536] (bf16) = embeds @ WihcatT + bias ----------------
__launch_bounds__(256, 2)
__global__ void k_gemm(const u16* __restrict__ A, const u16* __restrict__ Bw,
                       const float* __restrict__ biascat, u16* __restrict__ xg) {
    __shared__ u16 As[128 * 32];
    __shared__ u16 Bs[128 * 32];
    int tid = threadIdx.x;
    int lane = tid & 63, wid = tid >> 6;
    int l15 = lane & 15, q4 = lane >> 4;
    int bn = blockIdx.x;   // 24 tiles of N=3072
    int bm = blockIdx.y;   // 136 tiles of M=17408
    int wm = (wid >> 1) * 64, wn = (wid & 1) * 64;
    f32x4 acc[4][4] = {};
    for (int k0 = 0; k0 < ND; k0 += 32) {
        #pragma unroll
        for (int j = 0; j < 2; j++) {
            int fl = tid + j * 256;
            int row = fl >> 2, cb = fl & 3;
            const u16* ga = A + (size_t)(bm * 128 + row) * ND + k0 + cb * 8;
            gl_lds16(ga, &As[(size_t)(wid * 64 + j * 256) * 8]);
            const u16* gb = Bw + (size_t)(bn * 128 + row) * ND + k0 + cb * 8;
            gl_lds16(gb, &Bs[(size_t)(wid * 64 + j * 256) * 8]);
        }
        __syncthreads();
        bf16x8 af[4], bf[4];
        #pragma unroll
        for (int mt = 0; mt < 4; mt++)
            af[mt] = *(const bf16x8*)&As[(wm + mt * 16 + l15) * 32 + q4 * 8];
        #pragma unroll
        for (int nt = 0; nt < 4; nt++)
            bf[nt] = *(const bf16x8*)&Bs[(wn + nt * 16 + l15) * 32 + q4 * 8];
        #pragma unroll
        for (int mt = 0; mt < 4; mt++)
            #pragma unroll
            for (int nt = 0; nt < 4; nt++)
                acc[mt][nt] = __builtin_amdgcn_mfma_f32_16x16x32_bf16(af[mt], bf[nt], acc[mt][nt], 0, 0, 0);
        __syncthreads();
    }
    #pragma unroll
    for (int nt = 0; nt < 4; nt++) {
        int gn = bn * 128 + wn + nt * 16 + l15;
        int d = gn >= NG ? 1 : 0;
        int col = gn - d * NG;
        float bias = biascat[gn];
        #pragma unroll
        for (int mt = 0; mt < 4; mt++) {
            #pragma unroll
            for (int r = 0; r < 4; r++) {
                int m = bm * 128 + wm + mt * 16 + q4 * 4 + r;
                int b = m / S2, t = m - b * S2;
                float v = acc[mt][nt][r] + bias;
                xg[((size_t)(d * NB + b) * S2 + t) * NG + col] = f2b(v);
            }
        }
    }
}

// ---------------- recurrence: 32 WGs; cluster = (dir,batch-group) of 4 j-chunk WGs ----------------
// h exchange via agent-scope relaxed (sc1) atomics meeting at L3.
// NO acquire fence: ordering enforced by making af-load addresses data-dependent
// on the polled flag value (dep == 0 always, but HW/compiler can't know).
// Release side: __syncthreads drains vmcnt(0) (sc1 stores complete at L3) before
// the RELAXED flag add -> no buffer_wbl2, no buffer_inv, L2 (xg) stays warm.
__launch_bounds__(256, 1)
__global__ void k_recur(const u16* __restrict__ whhpack, const u16* __restrict__ xg,
                        const float* __restrict__ biascat, const u16* __restrict__ h0buf,
                        const float* __restrict__ c0, u16* __restrict__ hout,
                        int* __restrict__ flags) {
    int blk = blockIdx.x;      // 0..31
    int qc = blk >> 3;         // j-chunk 0..3
    int cl = blk & 7;          // cluster id (same bid%8 -> same-XCD heuristic)
    int d = cl >> 2;           // direction
    int g = cl & 3;            // batch group (16 batches)
    int tid = threadIdx.x, lane = tid & 63, w = tid >> 6;  // wave = gate type i,f,g,o
    int q4 = lane >> 4, l15 = lane & 15;

    __shared__ float preact[4][16 * 96];

    // stationary Whh B-fragments: 72 x 4 VGPR = 288 regs
    bf16x8 bfr[6][12];
    #pragma unroll
    for (int nt = 0; nt < 6; nt++)
        #pragma unroll
        for (int ks = 0; ks < 12; ks++)
            bfr[nt][ks] = *(const bf16x8*)(whhpack +
                ((size_t)((((d * 4 + qc) * 4 + w) * 6 + nt) * 12 + ks) * 64 + lane) * 8);

    // c-state in registers: 192 threads x 8 contiguous j-elements
    int bb = tid / 12;              // batch within group (tid<192)
    int j0 = (tid % 12) * 8;        // j offset within 96-chunk
    float cre[8];
    if (tid < 192) {
        const float* cp = c0 + (size_t)(d * NB + g * 16 + bb) * NH + qc * 96 + j0;
        #pragma unroll
        for (int e = 0; e < 8; e++) cre[e] = cp[e];
    }
    float biasreg[6];
    #pragma unroll
    for (int nt = 0; nt < 6; nt++)
        biasreg[nt] = biascat[d * NG + w * NH + qc * 96 + nt * 16 + l15];

    int* flagp = flags + cl * NS;
    const u16* hd = hout + (size_t)d * NB * NS * NH;
    const u16* xgd = xg + (size_t)d * NB * S2 * NG;

    float ci[6][4];
    auto preload = [&](int it2) {
        int s2 = d ? (NS - 1 - it2) : it2;
        if (s2 < S2) {
            const u16* xrow = xgd + ((size_t)(g * 16) * S2 + s2) * NG + w * NH + qc * 96 + l15;
            #pragma unroll
            for (int nt = 0; nt < 6; nt++)
                #pragma unroll
                for (int r = 0; r < 4; r++)
                    ci[nt][r] = b2f(xrow[(size_t)(q4 * 4 + r) * S2 * NG + nt * 16]);
        } else {
            #pragma unroll
            for (int nt = 0; nt < 6; nt++)
                #pragma unroll
                for (int r = 0; r < 4; r++) ci[nt][r] = biasreg[nt];
        }
    };
    preload(0);

    int dep = 0;   // always 0; carries the poll->load dependence
    #pragma unroll 1
    for (int it = 0; it < NS; ++it) {
        int s = d ? (NS - 1 - it) : it;
        int tprev = d ? (s + 1) : (s - 1);

        // A fragments: previous h (bf16), 16 batches x K=384
        bf16x8 af[12];
        if (it == 0) {
            const u16* hp = h0buf + (size_t)(d * NB + g * 16) * NH;
            #pragma unroll
            for (int ks = 0; ks < 12; ks++)
                af[ks] = *(const bf16x8*)(hp + (size_t)l15 * NH + ks * 32 + q4 * 8);
        } else {
            const u64* hp = (const u64*)(hd + ((size_t)(g * 16) * NS + tprev) * NH) + dep;
            #pragma unroll
            for (int ks = 0; ks < 12; ks++) {
                union { u64 q[2]; bf16x8 v; } u;
                const u64* p = hp + ((size_t)l15 * NS * NH + (size_t)ks * 32 + q4 * 8) / 4;
                u.q[0] = __hip_atomic_load(p,     __ATOMIC_RELAXED, __HIP_MEMORY_SCOPE_AGENT);
                u.q[1] = __hip_atomic_load(p + 1, __ATOMIC_RELAXED, __HIP_MEMORY_SCOPE_AGENT);
                af[ks] = u.v;
            }
        }

        f32x4 acc[6];
        #pragma unroll
        for (int nt = 0; nt < 6; nt++) {
            acc[nt][0] = ci[nt][0]; acc[nt][1] = ci[nt][1];
            acc[nt][2] = ci[nt][2]; acc[nt][3] = ci[nt][3];
        }
        #pragma unroll
        for (int ks = 0; ks < 12; ks++)
            #pragma unroll
            for (int nt = 0; nt < 6; nt++)
                acc[nt] = __builtin_amdgcn_mfma_f32_16x16x32_bf16(af[ks], bfr[nt][ks], acc[nt], 0, 0, 0);

        // preact (this wave's gate) -> LDS
        #pragma unroll
        for (int nt = 0; nt < 6; nt++)
            #pragma unroll
            for (int r = 0; r < 4; r++)
                preact[w][(q4 * 4 + r) * 96 + nt * 16 + l15] = acc[nt][r];
        __syncthreads();

        // cell update: 192 threads x 8 contiguous elements; h store via sc1 atomics
        if (tid < 192) {
            int idx = bb * 96 + j0;
            u16* ho = hout + (((size_t)(d * NB + g * 16 + bb)) * NS + s) * NH + qc * 96 + j0;
            union { u16 u[8]; u64 q[2]; } pk;
            #pragma unroll
            for (int e = 0; e < 8; e++) {
                float gi = preact[0][idx + e], gf = preact[1][idx + e];
                float gg = preact[2][idx + e], go = preact[3][idx + e];
                float c = cre[e];
                float cn = sigm(gf) * c + sigm(gi) * tanh_(gg);
                float hn = sigm(go) * tanh_(cn);
                cre[e] = cn;
                pk.u[e] = f2b(hn);
            }
            __hip_atomic_store((u64*)ho,     pk.q[0], __ATOMIC_RELAXED, __HIP_MEMORY_SCOPE_AGENT);
            __hip_atomic_store((u64*)ho + 1, pk.q[1], __ATOMIC_RELAXED, __HIP_MEMORY_SCOPE_AGENT);
        }
        __syncthreads();   // per-wave vmcnt(0) before s_barrier => all sc1 h stores at L3

        if (tid == 0)
            __hip_atomic_fetch_add(&flagp[it], 1, __ATOMIC_RELAXED, __HIP_MEMORY_SCOPE_AGENT);

        if (it == NS - 1) break;

        // prefetch next step's xg while waiting on siblings
        preload(it + 1);

        int fv = 4;
        if (lane == 0) {
            while ((fv = __hip_atomic_load(&flagp[it], __ATOMIC_RELAXED, __HIP_MEMORY_SCOPE_AGENT)) < 4)
                __builtin_amdgcn_s_sleep(1);
        }
        fv = __shfl(fv, 0);
        dep = fv - 4;      // == 0; next af loads depend on the poll result
    }
}

// ---------------- final linear: out[b,t,22] = [hf|hb] @ WlinT + blin ----------------
__global__ void k_final(const u16* __restrict__ hout, const float* __restrict__ wlin,
                        const float* __restrict__ blin, float* __restrict__ out) {
    int r = blockIdx.x * 256 + threadIdx.x;   // 0..32767
    int b = r >> 9, t = r & 511;
    const u16* hf = hout + ((size_t)b * NS + t) * NH;
    const u16* hb = hout + ((size_t)(NB + b) * NS + t) * NH;
    float acc[NT_OUT];
    #pragma unroll
    for (int tt = 0; tt < NT_OUT; tt++) acc[tt] = blin[tt];
    #pragma unroll 1
    for (int half = 0; half < 2; half++) {
        const u16* hp = half ? hb : hf;
        #pragma unroll 1
        for (int k8 = 0; k8 < NH / 8; k8++) {
            uint4 pk = *(const uint4*)(hp + k8 * 8);
            float x[8];
            x[0] = __uint_as_float(pk.x << 16); x[1] = __uint_as_float(pk.x & 0xffff0000u);
            x[2] = __uint_as_float(pk.y << 16); x[3] = __uint_as_float(pk.y & 0xffff0000u);
            x[4] = __uint_as_float(pk.z << 16); x[5] = __uint_as_float(pk.z & 0xffff0000u);
            x[6] = __uint_as_float(pk.w << 16); x[7] = __uint_as_float(pk.w & 0xffff0000u);
            int kk = half * NH + k8 * 8;
            #pragma unroll
            for (int e = 0; e < 8; e++)
                #pragma unroll
                for (int tt = 0; tt < NT_OUT; tt++)
                    acc[tt] += x[e] * wlin[tt * (2 * NH) + kk + e];   // uniform -> s_load
        }
    }
    float* op = out + (size_t)r * NT_OUT;
    #pragma unroll
    for (int tt = 0; tt < NT_OUT; tt++) op[tt] = acc[tt];
}

extern "C" void kernel_launch(void* const* d_in, const int* in_sizes, int n_in,
                              void* d_out, int out_size, void* d_ws, size_t ws_size,
                              hipStream_t stream) {
    const float* hidden = (const float*)d_in[0];
    const float* h0     = (const float*)d_in[1];
    const float* c0     = (const float*)d_in[2];
    const float* Wihf   = (const float*)d_in[3];
    const float* Whhf   = (const float*)d_in[4];
    const float* bihf   = (const float*)d_in[5];
    const float* bhhf   = (const float*)d_in[6];
    const float* Wihb   = (const float*)d_in[7];
    const float* Whhb   = (const float*)d_in[8];
    const float* bihb   = (const float*)d_in[9];
    const float* bhhb   = (const float*)d_in[10];
    const float* Wlin   = (const float*)d_in[11];
    const float* blin   = (const float*)d_in[12];
    const int* start_ids = (const int*)d_in[13];
    const int* masks     = (const int*)d_in[14];
    float* out = (float*)d_out;

    char* ws = (char*)d_ws;
    size_t off = 0;
    auto alloc = [&](size_t bytes) { void* p = ws + off; off += (bytes + 255) & ~(size_t)255; return p; };
    u16* embeds   = (u16*)alloc((size_t)MGEMM * ND * 2);           // 26.7 MB
    u16* wihcat   = (u16*)alloc((size_t)2 * NG * ND * 2);          // 4.7 MB
    float* biascat = (float*)alloc((size_t)2 * NG * 4);            // 12 KB
    u16* whhpack  = (u16*)alloc((size_t)2 * NG * NH * 2);          // 2.36 MB
    u16* h0buf    = (u16*)alloc((size_t)2 * NB * NH * 2);          // 98 KB
    u16* xg       = (u16*)alloc((size_t)2 * NB * S2 * NG * 2);     // 107 MB
    u16* hout     = (u16*)alloc((size_t)2 * NB * NS * NH * 2);     // 50.3 MB
    int* flags    = (int*)alloc((size_t)8 * NS * 4);               // 16 KB

    (void)hipMemsetAsync(flags, 0, (size_t)8 * NS * 4, stream);
    k_prep<<<256, 256, 0, stream>>>(hidden, start_ids, masks, embeds);
    k_weights<<<512, 256, 0, stream>>>(Wihf, Wihb, bihf, bhhf, bihb, bhhb, h0,
                                       wihcat, biascat, h0buf);
    k_packwhh<<<576, 256, 0, stream>>>(Whhf, Whhb, whhpack);
    dim3 ggrid(2 * NG / 128, MGEMM / 128);
    k_gemm<<<ggrid, 256, 0, stream>>>(embeds, wihcat, biascat, xg);
    k_recur<<<32, 256, 0, stream>>>(whhpack, xg, biascat, h0buf, c0, hout, flags);
    k_final<<<128, 256, 0, stream>>>(hout, Wlin, blin, out);
}